// Round 3
// baseline (622.053 us; speedup 1.0000x reference)
//
#include <hip/hip_runtime.h>
#include <hip/hip_bf16.h>
#include <math.h>

#define N_NODES 100000
#define EPS 1e-5f
#define BSH 6                       // 64 nodes per bucket
#define NPB 64
#define NBUCK ((N_NODES + NPB - 1) / NPB)  // 1563

typedef __attribute__((ext_vector_type(8))) short bf16x8;
typedef __attribute__((ext_vector_type(4))) float f32x4;

__device__ __forceinline__ float bflo(unsigned int u) { return __uint_as_float(u << 16); }
__device__ __forceinline__ float bfhi(unsigned int u) { return __uint_as_float(u & 0xffff0000u); }
__device__ __forceinline__ unsigned short fbits(float f) {
    __hip_bfloat16 h = __float2bfloat16(f);
    return *reinterpret_cast<unsigned short*>(&h);
}
__device__ __forceinline__ void stv(float* p, float y) { *p = y; }
__device__ __forceinline__ void stv(__hip_bfloat16* p, float y) { *p = __float2bfloat16(y); }

// ---------------- bucketed CSR build ----------------
__global__ void bucket_hist(const int* __restrict__ dst, int E, int* __restrict__ bcnt) {
    __shared__ int lh[NBUCK];
    for (int i = threadIdx.x; i < NBUCK; i += 256) lh[i] = 0;
    __syncthreads();
    for (int e = blockIdx.x * 256 + threadIdx.x; e < E; e += gridDim.x * 256)
        atomicAdd(&lh[dst[e] >> BSH], 1);
    __syncthreads();
    for (int i = threadIdx.x; i < NBUCK; i += 256) {
        int v = lh[i];
        if (v) atomicAdd(&bcnt[i], v);
    }
}

__global__ void bucket_scan(const int* __restrict__ bcnt, int* __restrict__ bbase,
                            int* __restrict__ row_ptr, int E) {
    __shared__ int s[1024];
    __shared__ int carry;
    int t = threadIdx.x;
    if (t == 0) carry = 0;
    __syncthreads();
    for (int base = 0; base < NBUCK; base += 1024) {
        int i = base + t;
        int v = (i < NBUCK) ? bcnt[i] : 0;
        s[t] = v;
        __syncthreads();
        for (int off = 1; off < 1024; off <<= 1) {
            int u = (t >= off) ? s[t - off] : 0;
            __syncthreads();
            s[t] += u;
            __syncthreads();
        }
        if (i < NBUCK) bbase[i] = carry + s[t] - v;
        __syncthreads();
        if (t == 1023) carry += s[t];
        __syncthreads();
    }
    if (t == 0) row_ptr[N_NODES] = E;
}

__global__ void bucket_scatter(const int* __restrict__ src, const int* __restrict__ dst, int E,
                               const int* __restrict__ bbase, int* __restrict__ bfill,
                               int2* __restrict__ pairs) {
    int e = blockIdx.x * 256 + threadIdx.x;
    if (e < E) {
        int d = dst[e];
        int b = d >> BSH;
        int p = bbase[b] + atomicAdd(&bfill[b], 1);
        pairs[p] = make_int2(src[e], d);
    }
}

__global__ void bucket_build(const int2* __restrict__ pairs, const int* __restrict__ bbase,
                             int* __restrict__ row_ptr, int* __restrict__ col, int E) {
    int b = blockIdx.x;
    int base = bbase[b];
    int cntb = ((b + 1 < NBUCK) ? bbase[b + 1] : E) - base;
    int node0 = b << BSH;
    __shared__ int lcnt[NPB];
    __shared__ int lofs[NPB];
    int t = threadIdx.x;
    if (t < NPB) lcnt[t] = 0;
    __syncthreads();
    for (int i = t; i < cntb; i += 256) atomicAdd(&lcnt[pairs[base + i].y - node0], 1);
    __syncthreads();
    if (t == 0) {
        int run = 0;
        for (int i = 0; i < NPB; i++) {
            lofs[i] = run;
            run += lcnt[i];
        }
    }
    __syncthreads();
    if (t < NPB) {
        int node = node0 + t;
        if (node < N_NODES) row_ptr[node] = base + lofs[t];
        lcnt[t] = 0;  // reuse as fill
    }
    __syncthreads();
    for (int i = t; i < cntb; i += 256) {
        int2 pr = pairs[base + i];
        int ln = pr.y - node0;
        int ofs = atomicAdd(&lcnt[ln], 1);
        col[base + lofs[ln] + ofs] = pr.x;
    }
}

// ---------------- aggregation ----------------
// layer1: x fp32, d=9; 7 lane-groups of 9 walk the edge list round-robin (MLP=7)
__global__ void agg9_kernel(const float* __restrict__ x, const int* __restrict__ row_ptr,
                            const int* __restrict__ col, float* __restrict__ mean, int n) {
    int node = (blockIdx.x * blockDim.x + threadIdx.x) >> 6;
    int lane = threadIdx.x & 63;
    int wv = threadIdx.x >> 6;
    __shared__ float red[4][64];
    float acc = 0.f;
    int start = 0, end = 0;
    if (node < n) {
        start = row_ptr[node];
        end = row_ptr[node + 1];
        int g = lane / 9;
        int f = lane - g * 9;
        if (g < 7) {
            for (int p = start + g; p < end; p += 7) acc += x[(size_t)col[p] * 9 + f];
        }
    }
    red[wv][lane] = acc;
    __syncthreads();
    if (node < n && lane < 9) {
        float s = red[wv][lane];
#pragma unroll
        for (int k = 1; k < 7; ++k) s += red[wv][lane + 9 * k];
        float inv = 1.f / fmaxf((float)(end - start), 1.f);
        mean[(size_t)node * 9 + lane] = s * inv;
    }
}

// bf16 d=64: one wave per node, lane = column, 8-deep unroll
__global__ void agg64_kernel(const unsigned short* __restrict__ h, const int* __restrict__ row_ptr,
                             const int* __restrict__ col, unsigned short* __restrict__ mean, int n) {
    int node = (blockIdx.x * blockDim.x + threadIdx.x) >> 6;
    int lane = threadIdx.x & 63;
    if (node >= n) return;
    int start = row_ptr[node], end = row_ptr[node + 1];
    float inv = 1.f / fmaxf((float)(end - start), 1.f);
    float acc = 0.f;
    int p = start;
    for (; p + 8 <= end; p += 8) {
        float v0 = bflo((unsigned int)h[(size_t)col[p] * 64 + lane]);
        float v1 = bflo((unsigned int)h[(size_t)col[p + 1] * 64 + lane]);
        float v2 = bflo((unsigned int)h[(size_t)col[p + 2] * 64 + lane]);
        float v3 = bflo((unsigned int)h[(size_t)col[p + 3] * 64 + lane]);
        float v4 = bflo((unsigned int)h[(size_t)col[p + 4] * 64 + lane]);
        float v5 = bflo((unsigned int)h[(size_t)col[p + 5] * 64 + lane]);
        float v6 = bflo((unsigned int)h[(size_t)col[p + 6] * 64 + lane]);
        float v7 = bflo((unsigned int)h[(size_t)col[p + 7] * 64 + lane]);
        acc += ((v0 + v1) + (v2 + v3)) + ((v4 + v5) + (v6 + v7));
    }
    for (; p < end; ++p) acc += bflo((unsigned int)h[(size_t)col[p] * 64 + lane]);
    mean[(size_t)node * 64 + lane] = fbits(acc * inv);
}

// bf16 d=128: one wave per node, lane covers 2 columns (4B load), 8-deep unroll
__global__ void agg128_kernel(const unsigned short* __restrict__ h, const int* __restrict__ row_ptr,
                              const int* __restrict__ col, unsigned short* __restrict__ mean, int n) {
    int node = (blockIdx.x * blockDim.x + threadIdx.x) >> 6;
    int lane = threadIdx.x & 63;
    if (node >= n) return;
    int start = row_ptr[node], end = row_ptr[node + 1];
    float inv = 1.f / fmaxf((float)(end - start), 1.f);
    float ax = 0.f, ay = 0.f;
    int p = start;
    for (; p + 8 <= end; p += 8) {
        unsigned int u0 = *(const unsigned int*)&h[(size_t)col[p] * 128 + lane * 2];
        unsigned int u1 = *(const unsigned int*)&h[(size_t)col[p + 1] * 128 + lane * 2];
        unsigned int u2 = *(const unsigned int*)&h[(size_t)col[p + 2] * 128 + lane * 2];
        unsigned int u3 = *(const unsigned int*)&h[(size_t)col[p + 3] * 128 + lane * 2];
        unsigned int u4 = *(const unsigned int*)&h[(size_t)col[p + 4] * 128 + lane * 2];
        unsigned int u5 = *(const unsigned int*)&h[(size_t)col[p + 5] * 128 + lane * 2];
        unsigned int u6 = *(const unsigned int*)&h[(size_t)col[p + 6] * 128 + lane * 2];
        unsigned int u7 = *(const unsigned int*)&h[(size_t)col[p + 7] * 128 + lane * 2];
        ax += ((bflo(u0) + bflo(u1)) + (bflo(u2) + bflo(u3))) +
              ((bflo(u4) + bflo(u5)) + (bflo(u6) + bflo(u7)));
        ay += ((bfhi(u0) + bfhi(u1)) + (bfhi(u2) + bfhi(u3))) +
              ((bfhi(u4) + bfhi(u5)) + (bfhi(u6) + bfhi(u7)));
    }
    for (; p < end; ++p) {
        unsigned int u = *(const unsigned int*)&h[(size_t)col[p] * 128 + lane * 2];
        ax += bflo(u);
        ay += bfhi(u);
    }
    unsigned int lo = fbits(ax * inv);
    unsigned int hi = fbits(ay * inv);
    *(unsigned int*)&mean[(size_t)node * 128 + lane * 2] = lo | (hi << 16);
}

// ---------------- weight prep ----------------
__global__ void wtrans_kernel(const float* __restrict__ wl, const float* __restrict__ wr,
                              int din, int dout, float* __restrict__ wt) {
    int i = blockIdx.x * blockDim.x + threadIdx.x;
    int K2 = 2 * din;
    if (i >= K2 * dout) return;
    int k = i / dout, j = i % dout;
    wt[k * dout + j] = (k < din) ? wl[j * din + k] : wr[j * din + (k - din)];
}

// bf16 MFMA B-fragment pack: bpack[t][ks][lane][e]
__global__ void packw_kernel(const float* __restrict__ wl, const float* __restrict__ wr,
                             int din, unsigned short* __restrict__ bpack) {
    int K2 = 2 * din;
    int total = K2 * 128;
    int i = blockIdx.x * 256 + threadIdx.x;
    if (i >= total) return;
    int e = i & 7;
    int lane = (i >> 3) & 63;
    int rest = i >> 9;
    int KSTEPS = din / 16;
    int t = rest / KSTEPS, ks = rest % KSTEPS;
    int j = t * 16 + (lane & 15);
    int k = ks * 32 + (lane >> 4) * 8 + e;
    float w = (k < din) ? wl[j * din + k] : wr[j * din + (k - din)];
    bpack[i] = fbits(w);
}

// ---------------- layer1 fp32 linear + LN + ReLU ----------------
template <int DIN, int DOUT, bool RELU, typename OT>
__global__ __launch_bounds__(256) void linear_ln_kernel(
    const float* __restrict__ meanp, const float* __restrict__ hp,
    const float* __restrict__ wt, const float* __restrict__ bias,
    const float* __restrict__ g, const float* __restrict__ be,
    OT* __restrict__ out, int n) {
    constexpr int K2 = 2 * DIN;
    constexpr int NCOL = DOUT / 4;
    constexpr int NROW = 256 / NCOL;
    constexpr int TN = 4 * NROW;
    constexpr int ASTR = TN + 4;
    constexpr int OSTR = DOUT + 4;
    constexpr int SMEMF = (K2 * ASTR > TN * OSTR) ? K2 * ASTR : TN * OSTR;
    __shared__ float smem[SMEMF];

    int tid = threadIdx.x;
    int n0base = blockIdx.x * TN;

    for (int idx = tid; idx < TN * K2; idx += 256) {
        int nn = idx / K2;
        int k = idx % K2;
        int node = n0base + nn;
        float v = 0.f;
        if (node < n)
            v = (k < DIN) ? meanp[(size_t)node * DIN + k] : hp[(size_t)node * DIN + (k - DIN)];
        smem[k * ASTR + nn] = v;
    }
    __syncthreads();

    int colt = tid % NCOL;
    int rowt = tid / NCOL;
    int j0 = colt * 4;
    int nn0 = rowt * 4;

    float acc[4][4];
#pragma unroll
    for (int i = 0; i < 4; ++i)
#pragma unroll
        for (int j = 0; j < 4; ++j) acc[i][j] = 0.f;

#pragma unroll 2
    for (int k = 0; k < K2; ++k) {
        float4 a = *(const float4*)&smem[k * ASTR + nn0];
        float4 w = *(const float4*)&wt[k * DOUT + j0];
        acc[0][0] = fmaf(a.x, w.x, acc[0][0]);
        acc[0][1] = fmaf(a.x, w.y, acc[0][1]);
        acc[0][2] = fmaf(a.x, w.z, acc[0][2]);
        acc[0][3] = fmaf(a.x, w.w, acc[0][3]);
        acc[1][0] = fmaf(a.y, w.x, acc[1][0]);
        acc[1][1] = fmaf(a.y, w.y, acc[1][1]);
        acc[1][2] = fmaf(a.y, w.z, acc[1][2]);
        acc[1][3] = fmaf(a.y, w.w, acc[1][3]);
        acc[2][0] = fmaf(a.z, w.x, acc[2][0]);
        acc[2][1] = fmaf(a.z, w.y, acc[2][1]);
        acc[2][2] = fmaf(a.z, w.z, acc[2][2]);
        acc[2][3] = fmaf(a.z, w.w, acc[2][3]);
        acc[3][0] = fmaf(a.w, w.x, acc[3][0]);
        acc[3][1] = fmaf(a.w, w.y, acc[3][1]);
        acc[3][2] = fmaf(a.w, w.z, acc[3][2]);
        acc[3][3] = fmaf(a.w, w.w, acc[3][3]);
    }
    __syncthreads();

    float4 bj = *(const float4*)&bias[j0];
#pragma unroll
    for (int i = 0; i < 4; ++i) {
        float4 o;
        o.x = acc[i][0] + bj.x;
        o.y = acc[i][1] + bj.y;
        o.z = acc[i][2] + bj.z;
        o.w = acc[i][3] + bj.w;
        *(float4*)&smem[(nn0 + i) * OSTR + j0] = o;
    }
    __syncthreads();

    int wid = tid >> 6, lane = tid & 63;
    for (int nn = wid; nn < TN; nn += 4) {
        int node = n0base + nn;
        if (node >= n) continue;
        float v0 = smem[nn * OSTR + lane];
        float v1 = (DOUT == 128) ? smem[nn * OSTR + 64 + lane] : 0.f;
        float s = v0 + v1;
        float ss = v0 * v0 + v1 * v1;
#pragma unroll
        for (int off = 32; off > 0; off >>= 1) {
            s += __shfl_xor(s, off);
            ss += __shfl_xor(ss, off);
        }
        float mu = s / DOUT;
        float var = ss / DOUT - mu * mu;
        float inv = rsqrtf(var + EPS);
        float y0 = (v0 - mu) * inv * g[lane] + be[lane];
        if (RELU) y0 = fmaxf(y0, 0.f);
        stv(&out[(size_t)node * DOUT + lane], y0);
        if (DOUT == 128) {
            float y1 = (v1 - mu) * inv * g[64 + lane] + be[64 + lane];
            if (RELU) y1 = fmaxf(y1, 0.f);
            stv(&out[(size_t)node * DOUT + 64 + lane], y1);
        }
    }
}

// ---------------- bf16 MFMA linear (concat-K) + LN + optional ReLU ----------
template <int DIN, bool RELU, typename OT>
__global__ __launch_bounds__(256) void mfma_linear_ln(
    const unsigned short* __restrict__ meanb, const unsigned short* __restrict__ hb,
    const unsigned short* __restrict__ bpack, const float* __restrict__ bias,
    const float* __restrict__ g, const float* __restrict__ be, OT* __restrict__ out, int n) {
    constexpr int KSTEPS = DIN / 16;
    int tid = threadIdx.x;
    int w = tid >> 6, l = tid & 63;
    int n0 = blockIdx.x * 64 + w * 16;
    int arow = l & 15;
    int koff = (l >> 4) * 8;
    int anode = n0 + arow;
    if (anode >= n) anode = n - 1;
    const unsigned short* mrow = meanb + (size_t)anode * DIN;
    const unsigned short* hrow = hb + (size_t)anode * DIN;

    f32x4 acc[8];
#pragma unroll
    for (int t = 0; t < 8; ++t) acc[t] = (f32x4){0.f, 0.f, 0.f, 0.f};

#pragma unroll
    for (int ks = 0; ks < KSTEPS; ++ks) {
        int k = ks * 32 + koff;
        const unsigned short* ap = (k < DIN) ? (mrow + k) : (hrow + (k - DIN));
        bf16x8 a = *(const bf16x8*)ap;
#pragma unroll
        for (int t = 0; t < 8; ++t) {
            bf16x8 b = *(const bf16x8*)(bpack + (((size_t)t * KSTEPS + ks) * 64 + l) * 8);
            acc[t] = __builtin_amdgcn_mfma_f32_16x16x32_bf16(a, b, acc[t], 0, 0, 0);
        }
    }

    int jbase = l & 15;
    float bj[8], gj[8], bej[8];
#pragma unroll
    for (int t = 0; t < 8; ++t) {
        bj[t] = bias[t * 16 + jbase];
        gj[t] = g[t * 16 + jbase];
        bej[t] = be[t * 16 + jbase];
    }
#pragma unroll
    for (int r = 0; r < 4; ++r) {
        float v[8];
        float s = 0.f, ss = 0.f;
#pragma unroll
        for (int t = 0; t < 8; ++t) {
            v[t] = acc[t][r] + bj[t];
            s += v[t];
            ss += v[t] * v[t];
        }
#pragma unroll
        for (int off = 1; off < 16; off <<= 1) {
            s += __shfl_xor(s, off);
            ss += __shfl_xor(ss, off);
        }
        float mu = s * (1.f / 128.f);
        float var = ss * (1.f / 128.f) - mu * mu;
        float inv = rsqrtf(var + EPS);
        int node = n0 + (l >> 4) * 4 + r;
        if (node < n) {
#pragma unroll
            for (int t = 0; t < 8; ++t) {
                float y = (v[t] - mu) * inv * gj[t] + bej[t];
                if (RELU) y = fmaxf(y, 0.f);
                stv(&out[(size_t)node * 128 + t * 16 + jbase], y);
            }
        }
    }
}

extern "C" void kernel_launch(void* const* d_in, const int* in_sizes, int n_in,
                              void* d_out, int out_size, void* d_ws, size_t ws_size,
                              hipStream_t stream) {
    const float* x = (const float*)d_in[0];
    const int* edge = (const int*)d_in[1];
    int E = in_sizes[1] / 2;
    const int* src = edge;
    const int* dst = edge + E;

    const float* w1l = (const float*)d_in[2];
    const float* b1  = (const float*)d_in[3];
    const float* w1r = (const float*)d_in[4];
    const float* g1  = (const float*)d_in[5];
    const float* be1 = (const float*)d_in[6];
    const float* w2l = (const float*)d_in[7];
    const float* b2  = (const float*)d_in[8];
    const float* w2r = (const float*)d_in[9];
    const float* g2  = (const float*)d_in[10];
    const float* be2 = (const float*)d_in[11];
    const float* w3l = (const float*)d_in[12];
    const float* b3  = (const float*)d_in[13];
    const float* w3r = (const float*)d_in[14];
    const float* g3  = (const float*)d_in[15];
    const float* be3 = (const float*)d_in[16];
    const float* w4l = (const float*)d_in[17];
    const float* b4  = (const float*)d_in[18];
    const float* w4r = (const float*)d_in[19];
    const float* g4  = (const float*)d_in[20];
    const float* be4 = (const float*)d_in[21];

    char* ws = (char*)d_ws;
    size_t off = 0;
    auto alloc = [&](size_t bytes) {
        void* p = ws + off;
        off = (off + bytes + 255) & ~(size_t)255;
        return p;
    };
    int* row_ptr = (int*)alloc((N_NODES + 1) * sizeof(int));
    int* bcnt    = (int*)alloc(NBUCK * sizeof(int));
    int* bbase   = (int*)alloc(NBUCK * sizeof(int));
    int* bfill   = (int*)alloc(NBUCK * sizeof(int));
    int2* pairs  = (int2*)alloc((size_t)E * sizeof(int2));
    int* colx    = (int*)alloc((size_t)E * sizeof(int));
    float* wt1   = (float*)alloc(18 * 64 * sizeof(float));
    unsigned short* bp2 = (unsigned short*)alloc(128 * 128 * sizeof(short));
    unsigned short* bp3 = (unsigned short*)alloc(256 * 128 * sizeof(short));
    unsigned short* bp4 = (unsigned short*)alloc(256 * 128 * sizeof(short));
    float* m9    = (float*)alloc((size_t)N_NODES * 9 * sizeof(float));
    unsigned short* mbf = (unsigned short*)alloc((size_t)N_NODES * 128 * sizeof(short));
    unsigned short* h1  = (unsigned short*)alloc((size_t)N_NODES * 64 * sizeof(short));
    unsigned short* h2  = (unsigned short*)alloc((size_t)N_NODES * 128 * sizeof(short));
    unsigned short* h3  = (unsigned short*)alloc((size_t)N_NODES * 128 * sizeof(short));
    (void)ws_size;

    hipMemsetAsync(bcnt, 0, NBUCK * sizeof(int), stream);
    hipMemsetAsync(bfill, 0, NBUCK * sizeof(int), stream);

    int EB = (E + 255) / 256;
    bucket_hist<<<304, 256, 0, stream>>>(dst, E, bcnt);
    bucket_scan<<<1, 1024, 0, stream>>>(bcnt, bbase, row_ptr, E);
    bucket_scatter<<<EB, 256, 0, stream>>>(src, dst, E, bbase, bfill, pairs);
    bucket_build<<<NBUCK, 256, 0, stream>>>(pairs, bbase, row_ptr, colx, E);

    wtrans_kernel<<<(18 * 64 + 255) / 256, 256, 0, stream>>>(w1l, w1r, 9, 64, wt1);
    packw_kernel<<<(128 * 128 + 255) / 256, 256, 0, stream>>>(w2l, w2r, 64, bp2);
    packw_kernel<<<(256 * 128 + 255) / 256, 256, 0, stream>>>(w3l, w3r, 128, bp3);
    packw_kernel<<<(256 * 128 + 255) / 256, 256, 0, stream>>>(w4l, w4r, 128, bp4);

    float* out = (float*)d_out;
    int AGB = (N_NODES * 64 + 255) / 256;  // one wave per node
    int LNB = (N_NODES + 63) / 64;         // 64 nodes per block

    // layer 1: 9 -> 64 (fp32 compute, bf16 out)
    agg9_kernel<<<AGB, 256, 0, stream>>>(x, row_ptr, colx, m9, N_NODES);
    linear_ln_kernel<9, 64, true, __hip_bfloat16><<<LNB, 256, 0, stream>>>(
        m9, x, wt1, b1, g1, be1, (__hip_bfloat16*)h1, N_NODES);
    // layer 2: 64 -> 128
    agg64_kernel<<<AGB, 256, 0, stream>>>(h1, row_ptr, colx, mbf, N_NODES);
    mfma_linear_ln<64, true, __hip_bfloat16><<<LNB, 256, 0, stream>>>(
        mbf, h1, bp2, b2, g2, be2, (__hip_bfloat16*)h2, N_NODES);
    // layer 3: 128 -> 128
    agg128_kernel<<<AGB, 256, 0, stream>>>(h2, row_ptr, colx, mbf, N_NODES);
    mfma_linear_ln<128, true, __hip_bfloat16><<<LNB, 256, 0, stream>>>(
        mbf, h2, bp3, b3, g3, be3, (__hip_bfloat16*)h3, N_NODES);
    // layer 4: 128 -> 128 (no ReLU, fp32 out)
    agg128_kernel<<<AGB, 256, 0, stream>>>(h3, row_ptr, colx, mbf, N_NODES);
    mfma_linear_ln<128, false, float><<<LNB, 256, 0, stream>>>(
        mbf, h3, bp4, b4, g4, be4, out, N_NODES);
}

// Round 4
// 418.399 us; speedup vs baseline: 1.4867x; 1.4867x over previous
//
#include <hip/hip_runtime.h>
#include <hip/hip_bf16.h>
#include <math.h>

#define N_NODES 100000
#define EPS 1e-5f
#define B2SH 11
#define NPB2 2048
#define NBUCK2 ((N_NODES + NPB2 - 1) / NPB2)  // 49
#define NPART 256

typedef __attribute__((ext_vector_type(8))) short bf16x8;
typedef __attribute__((ext_vector_type(4))) float f32x4;

__device__ __forceinline__ float bflo(unsigned int u) { return __uint_as_float(u << 16); }
__device__ __forceinline__ float bfhi(unsigned int u) { return __uint_as_float(u & 0xffff0000u); }
__device__ __forceinline__ unsigned short fbits(float f) {
    __hip_bfloat16 h = __float2bfloat16(f);
    return *reinterpret_cast<unsigned short*>(&h);
}
__device__ __forceinline__ void stv(float* p, float y) { *p = y; }
__device__ __forceinline__ void stv(__hip_bfloat16* p, float y) { *p = __float2bfloat16(y); }

// ---------------- atomic-free two-level CSR build ----------------
// Pass A: per-block coarse histogram (49 buckets of 2048 nodes)
__global__ void part_hist(const int* __restrict__ dst, int E, int* __restrict__ blkhist) {
    __shared__ int h[NBUCK2];
    int b = blockIdx.x;
    int slice = (E + NPART - 1) / NPART;
    int s0 = b * slice;
    int s1 = min(E, s0 + slice);
    for (int i = threadIdx.x; i < NBUCK2; i += 256) h[i] = 0;
    __syncthreads();
    for (int e = s0 + threadIdx.x; e < s1; e += 256) atomicAdd(&h[dst[e] >> B2SH], 1);
    __syncthreads();
    for (int i = threadIdx.x; i < NBUCK2; i += 256) blkhist[i * NPART + b] = h[i];
}

// Pass B: per-(bucket,block) write cursors + bucket bases. One block, deterministic.
__global__ void part_offsets(const int* __restrict__ blkhist, int* __restrict__ blkoffs,
                             int* __restrict__ bbase2, int* __restrict__ row_ptr, int E) {
    __shared__ int tot[NBUCK2];
    __shared__ int sbase[NBUCK2 + 1];
    int j = threadIdx.x;
    if (j < NBUCK2) {
        int run = 0;
#pragma unroll 8
        for (int b = 0; b < NPART; ++b) {
            blkoffs[j * NPART + b] = run;
            run += blkhist[j * NPART + b];
        }
        tot[j] = run;
    }
    __syncthreads();
    if (j == 0) {
        int run = 0;
        for (int i = 0; i < NBUCK2; ++i) {
            sbase[i] = run;
            run += tot[i];
        }
        sbase[NBUCK2] = run;
        row_ptr[N_NODES] = E;
    }
    __syncthreads();
    if (j <= NBUCK2) bbase2[j] = sbase[j];
    if (j < NBUCK2) {
        int base = sbase[j];
#pragma unroll 8
        for (int b = 0; b < NPART; ++b) blkoffs[j * NPART + b] += base;
    }
}

// Pass C: scatter packed (src<<11 | local_dst) into pre-reserved per-bucket regions
__global__ void part_scatter(const int* __restrict__ src, const int* __restrict__ dst, int E,
                             const int* __restrict__ blkoffs, unsigned int* __restrict__ pairs) {
    __shared__ int pos[NBUCK2];
    int b = blockIdx.x;
    int slice = (E + NPART - 1) / NPART;
    int s0 = b * slice;
    int s1 = min(E, s0 + slice);
    for (int i = threadIdx.x; i < NBUCK2; i += 256) pos[i] = blkoffs[i * NPART + b];
    __syncthreads();
    for (int e = s0 + threadIdx.x; e < s1; e += 256) {
        int d = dst[e];
        int jb = d >> B2SH;
        int p = atomicAdd(&pos[jb], 1);
        pairs[p] = ((unsigned int)src[e] << B2SH) | (unsigned int)(d & (NPB2 - 1));
    }
}

// Pass D: per-bucket local CSR build (all traffic in a ~128 KB L2-hot window)
__global__ __launch_bounds__(1024) void bucket_build2(const unsigned int* __restrict__ pairs,
                                                      const int* __restrict__ bbase2,
                                                      int* __restrict__ row_ptr,
                                                      int* __restrict__ col) {
    __shared__ int lcnt[NPB2];
    __shared__ int lofs[NPB2];
    __shared__ int part[1024];
    int bk = blockIdx.x;
    int base = bbase2[bk];
    int cntb = bbase2[bk + 1] - base;
    int node0 = bk << B2SH;
    int t = threadIdx.x;
    lcnt[t] = 0;
    lcnt[t + 1024] = 0;
    __syncthreads();
    for (int i = t; i < cntb; i += 1024) atomicAdd(&lcnt[pairs[base + i] & (NPB2 - 1)], 1);
    __syncthreads();
    int a0 = lcnt[2 * t], a1 = lcnt[2 * t + 1];
    part[t] = a0 + a1;
    __syncthreads();
    for (int off = 1; off < 1024; off <<= 1) {
        int v = (t >= off) ? part[t - off] : 0;
        __syncthreads();
        part[t] += v;
        __syncthreads();
    }
    int excl = part[t] - (a0 + a1);
    lofs[2 * t] = excl;
    lofs[2 * t + 1] = excl + a0;
    __syncthreads();
#pragma unroll
    for (int k = 0; k < 2; ++k) {
        int ln = 2 * t + k;
        int node = node0 + ln;
        if (node < N_NODES) row_ptr[node] = base + lofs[ln];
    }
    lcnt[t] = 0;
    lcnt[t + 1024] = 0;
    __syncthreads();
    for (int i = t; i < cntb; i += 1024) {
        unsigned int v = pairs[base + i];
        int ld = v & (NPB2 - 1);
        int s = v >> B2SH;
        int p = base + lofs[ld] + atomicAdd(&lcnt[ld], 1);
        col[p] = s;
    }
}

// ---------------- aggregation ----------------
// layer1: x fp32, d=9; 7 lane-groups of 9 walk the edge list round-robin (MLP=7)
__global__ void agg9_kernel(const float* __restrict__ x, const int* __restrict__ row_ptr,
                            const int* __restrict__ col, float* __restrict__ mean, int n) {
    int node = (blockIdx.x * blockDim.x + threadIdx.x) >> 6;
    int lane = threadIdx.x & 63;
    int wv = threadIdx.x >> 6;
    __shared__ float red[4][64];
    float acc = 0.f;
    int start = 0, end = 0;
    if (node < n) {
        start = row_ptr[node];
        end = row_ptr[node + 1];
        int g = lane / 9;
        int f = lane - g * 9;
        if (g < 7) {
            for (int p = start + g; p < end; p += 7) acc += x[(size_t)col[p] * 9 + f];
        }
    }
    red[wv][lane] = acc;
    __syncthreads();
    if (node < n && lane < 9) {
        float s = red[wv][lane];
#pragma unroll
        for (int k = 1; k < 7; ++k) s += red[wv][lane + 9 * k];
        float inv = 1.f / fmaxf((float)(end - start), 1.f);
        mean[(size_t)node * 9 + lane] = s * inv;
    }
}

// bf16 d=64: one wave per node, lane = column, 8-deep unroll
__global__ void agg64_kernel(const unsigned short* __restrict__ h, const int* __restrict__ row_ptr,
                             const int* __restrict__ col, unsigned short* __restrict__ mean, int n) {
    int node = (blockIdx.x * blockDim.x + threadIdx.x) >> 6;
    int lane = threadIdx.x & 63;
    if (node >= n) return;
    int start = row_ptr[node], end = row_ptr[node + 1];
    float inv = 1.f / fmaxf((float)(end - start), 1.f);
    float acc = 0.f;
    int p = start;
    for (; p + 8 <= end; p += 8) {
        float v0 = bflo((unsigned int)h[(size_t)col[p] * 64 + lane]);
        float v1 = bflo((unsigned int)h[(size_t)col[p + 1] * 64 + lane]);
        float v2 = bflo((unsigned int)h[(size_t)col[p + 2] * 64 + lane]);
        float v3 = bflo((unsigned int)h[(size_t)col[p + 3] * 64 + lane]);
        float v4 = bflo((unsigned int)h[(size_t)col[p + 4] * 64 + lane]);
        float v5 = bflo((unsigned int)h[(size_t)col[p + 5] * 64 + lane]);
        float v6 = bflo((unsigned int)h[(size_t)col[p + 6] * 64 + lane]);
        float v7 = bflo((unsigned int)h[(size_t)col[p + 7] * 64 + lane]);
        acc += ((v0 + v1) + (v2 + v3)) + ((v4 + v5) + (v6 + v7));
    }
    for (; p < end; ++p) acc += bflo((unsigned int)h[(size_t)col[p] * 64 + lane]);
    mean[(size_t)node * 64 + lane] = fbits(acc * inv);
}

// bf16 d=128: one wave per node, lane covers 2 columns (4B load), 8-deep unroll
__global__ void agg128_kernel(const unsigned short* __restrict__ h, const int* __restrict__ row_ptr,
                              const int* __restrict__ col, unsigned short* __restrict__ mean, int n) {
    int node = (blockIdx.x * blockDim.x + threadIdx.x) >> 6;
    int lane = threadIdx.x & 63;
    if (node >= n) return;
    int start = row_ptr[node], end = row_ptr[node + 1];
    float inv = 1.f / fmaxf((float)(end - start), 1.f);
    float ax = 0.f, ay = 0.f;
    int p = start;
    for (; p + 8 <= end; p += 8) {
        unsigned int u0 = *(const unsigned int*)&h[(size_t)col[p] * 128 + lane * 2];
        unsigned int u1 = *(const unsigned int*)&h[(size_t)col[p + 1] * 128 + lane * 2];
        unsigned int u2 = *(const unsigned int*)&h[(size_t)col[p + 2] * 128 + lane * 2];
        unsigned int u3 = *(const unsigned int*)&h[(size_t)col[p + 3] * 128 + lane * 2];
        unsigned int u4 = *(const unsigned int*)&h[(size_t)col[p + 4] * 128 + lane * 2];
        unsigned int u5 = *(const unsigned int*)&h[(size_t)col[p + 5] * 128 + lane * 2];
        unsigned int u6 = *(const unsigned int*)&h[(size_t)col[p + 6] * 128 + lane * 2];
        unsigned int u7 = *(const unsigned int*)&h[(size_t)col[p + 7] * 128 + lane * 2];
        ax += ((bflo(u0) + bflo(u1)) + (bflo(u2) + bflo(u3))) +
              ((bflo(u4) + bflo(u5)) + (bflo(u6) + bflo(u7)));
        ay += ((bfhi(u0) + bfhi(u1)) + (bfhi(u2) + bfhi(u3))) +
              ((bfhi(u4) + bfhi(u5)) + (bfhi(u6) + bfhi(u7)));
    }
    for (; p < end; ++p) {
        unsigned int u = *(const unsigned int*)&h[(size_t)col[p] * 128 + lane * 2];
        ax += bflo(u);
        ay += bfhi(u);
    }
    unsigned int lo = fbits(ax * inv);
    unsigned int hi = fbits(ay * inv);
    *(unsigned int*)&mean[(size_t)node * 128 + lane * 2] = lo | (hi << 16);
}

// ---------------- weight prep ----------------
__global__ void wtrans_kernel(const float* __restrict__ wl, const float* __restrict__ wr,
                              int din, int dout, float* __restrict__ wt) {
    int i = blockIdx.x * blockDim.x + threadIdx.x;
    int K2 = 2 * din;
    if (i >= K2 * dout) return;
    int k = i / dout, j = i % dout;
    wt[k * dout + j] = (k < din) ? wl[j * din + k] : wr[j * din + (k - din)];
}

// bf16 MFMA B-fragment pack: bpack[t][ks][lane][e]
__global__ void packw_kernel(const float* __restrict__ wl, const float* __restrict__ wr,
                             int din, unsigned short* __restrict__ bpack) {
    int K2 = 2 * din;
    int total = K2 * 128;
    int i = blockIdx.x * 256 + threadIdx.x;
    if (i >= total) return;
    int e = i & 7;
    int lane = (i >> 3) & 63;
    int rest = i >> 9;
    int KSTEPS = din / 16;
    int t = rest / KSTEPS, ks = rest % KSTEPS;
    int j = t * 16 + (lane & 15);
    int k = ks * 32 + (lane >> 4) * 8 + e;
    float w = (k < din) ? wl[j * din + k] : wr[j * din + (k - din)];
    bpack[i] = fbits(w);
}

// ---------------- layer1 fp32 linear + LN + ReLU ----------------
template <int DIN, int DOUT, bool RELU, typename OT>
__global__ __launch_bounds__(256) void linear_ln_kernel(
    const float* __restrict__ meanp, const float* __restrict__ hp,
    const float* __restrict__ wt, const float* __restrict__ bias,
    const float* __restrict__ g, const float* __restrict__ be,
    OT* __restrict__ out, int n) {
    constexpr int K2 = 2 * DIN;
    constexpr int NCOL = DOUT / 4;
    constexpr int NROW = 256 / NCOL;
    constexpr int TN = 4 * NROW;
    constexpr int ASTR = TN + 4;
    constexpr int OSTR = DOUT + 4;
    constexpr int SMEMF = (K2 * ASTR > TN * OSTR) ? K2 * ASTR : TN * OSTR;
    __shared__ float smem[SMEMF];

    int tid = threadIdx.x;
    int n0base = blockIdx.x * TN;

    for (int idx = tid; idx < TN * K2; idx += 256) {
        int nn = idx / K2;
        int k = idx % K2;
        int node = n0base + nn;
        float v = 0.f;
        if (node < n)
            v = (k < DIN) ? meanp[(size_t)node * DIN + k] : hp[(size_t)node * DIN + (k - DIN)];
        smem[k * ASTR + nn] = v;
    }
    __syncthreads();

    int colt = tid % NCOL;
    int rowt = tid / NCOL;
    int j0 = colt * 4;
    int nn0 = rowt * 4;

    float acc[4][4];
#pragma unroll
    for (int i = 0; i < 4; ++i)
#pragma unroll
        for (int j = 0; j < 4; ++j) acc[i][j] = 0.f;

#pragma unroll 2
    for (int k = 0; k < K2; ++k) {
        float4 a = *(const float4*)&smem[k * ASTR + nn0];
        float4 w = *(const float4*)&wt[k * DOUT + j0];
        acc[0][0] = fmaf(a.x, w.x, acc[0][0]);
        acc[0][1] = fmaf(a.x, w.y, acc[0][1]);
        acc[0][2] = fmaf(a.x, w.z, acc[0][2]);
        acc[0][3] = fmaf(a.x, w.w, acc[0][3]);
        acc[1][0] = fmaf(a.y, w.x, acc[1][0]);
        acc[1][1] = fmaf(a.y, w.y, acc[1][1]);
        acc[1][2] = fmaf(a.y, w.z, acc[1][2]);
        acc[1][3] = fmaf(a.y, w.w, acc[1][3]);
        acc[2][0] = fmaf(a.z, w.x, acc[2][0]);
        acc[2][1] = fmaf(a.z, w.y, acc[2][1]);
        acc[2][2] = fmaf(a.z, w.z, acc[2][2]);
        acc[2][3] = fmaf(a.z, w.w, acc[2][3]);
        acc[3][0] = fmaf(a.w, w.x, acc[3][0]);
        acc[3][1] = fmaf(a.w, w.y, acc[3][1]);
        acc[3][2] = fmaf(a.w, w.z, acc[3][2]);
        acc[3][3] = fmaf(a.w, w.w, acc[3][3]);
    }
    __syncthreads();

    float4 bj = *(const float4*)&bias[j0];
#pragma unroll
    for (int i = 0; i < 4; ++i) {
        float4 o;
        o.x = acc[i][0] + bj.x;
        o.y = acc[i][1] + bj.y;
        o.z = acc[i][2] + bj.z;
        o.w = acc[i][3] + bj.w;
        *(float4*)&smem[(nn0 + i) * OSTR + j0] = o;
    }
    __syncthreads();

    int wid = tid >> 6, lane = tid & 63;
    for (int nn = wid; nn < TN; nn += 4) {
        int node = n0base + nn;
        if (node >= n) continue;
        float v0 = smem[nn * OSTR + lane];
        float v1 = (DOUT == 128) ? smem[nn * OSTR + 64 + lane] : 0.f;
        float s = v0 + v1;
        float ss = v0 * v0 + v1 * v1;
#pragma unroll
        for (int off = 32; off > 0; off >>= 1) {
            s += __shfl_xor(s, off);
            ss += __shfl_xor(ss, off);
        }
        float mu = s / DOUT;
        float var = ss / DOUT - mu * mu;
        float inv = rsqrtf(var + EPS);
        float y0 = (v0 - mu) * inv * g[lane] + be[lane];
        if (RELU) y0 = fmaxf(y0, 0.f);
        stv(&out[(size_t)node * DOUT + lane], y0);
        if (DOUT == 128) {
            float y1 = (v1 - mu) * inv * g[64 + lane] + be[64 + lane];
            if (RELU) y1 = fmaxf(y1, 0.f);
            stv(&out[(size_t)node * DOUT + 64 + lane], y1);
        }
    }
}

// ---------------- bf16 MFMA linear (concat-K) + LN + optional ReLU ----------
template <int DIN, bool RELU, typename OT>
__global__ __launch_bounds__(256) void mfma_linear_ln(
    const unsigned short* __restrict__ meanb, const unsigned short* __restrict__ hb,
    const unsigned short* __restrict__ bpack, const float* __restrict__ bias,
    const float* __restrict__ g, const float* __restrict__ be, OT* __restrict__ out, int n) {
    constexpr int KSTEPS = DIN / 16;
    int tid = threadIdx.x;
    int w = tid >> 6, l = tid & 63;
    int n0 = blockIdx.x * 64 + w * 16;
    int arow = l & 15;
    int koff = (l >> 4) * 8;
    int anode = n0 + arow;
    if (anode >= n) anode = n - 1;
    const unsigned short* mrow = meanb + (size_t)anode * DIN;
    const unsigned short* hrow = hb + (size_t)anode * DIN;

    f32x4 acc[8];
#pragma unroll
    for (int t = 0; t < 8; ++t) acc[t] = (f32x4){0.f, 0.f, 0.f, 0.f};

#pragma unroll
    for (int ks = 0; ks < KSTEPS; ++ks) {
        int k = ks * 32 + koff;
        const unsigned short* ap = (k < DIN) ? (mrow + k) : (hrow + (k - DIN));
        bf16x8 a = *(const bf16x8*)ap;
#pragma unroll
        for (int t = 0; t < 8; ++t) {
            bf16x8 b = *(const bf16x8*)(bpack + (((size_t)t * KSTEPS + ks) * 64 + l) * 8);
            acc[t] = __builtin_amdgcn_mfma_f32_16x16x32_bf16(a, b, acc[t], 0, 0, 0);
        }
    }

    int jbase = l & 15;
    float bj[8], gj[8], bej[8];
#pragma unroll
    for (int t = 0; t < 8; ++t) {
        bj[t] = bias[t * 16 + jbase];
        gj[t] = g[t * 16 + jbase];
        bej[t] = be[t * 16 + jbase];
    }
#pragma unroll
    for (int r = 0; r < 4; ++r) {
        float v[8];
        float s = 0.f, ss = 0.f;
#pragma unroll
        for (int t = 0; t < 8; ++t) {
            v[t] = acc[t][r] + bj[t];
            s += v[t];
            ss += v[t] * v[t];
        }
#pragma unroll
        for (int off = 1; off < 16; off <<= 1) {
            s += __shfl_xor(s, off);
            ss += __shfl_xor(ss, off);
        }
        float mu = s * (1.f / 128.f);
        float var = ss * (1.f / 128.f) - mu * mu;
        float inv = rsqrtf(var + EPS);
        int node = n0 + (l >> 4) * 4 + r;
        if (node < n) {
#pragma unroll
            for (int t = 0; t < 8; ++t) {
                float y = (v[t] - mu) * inv * gj[t] + bej[t];
                if (RELU) y = fmaxf(y, 0.f);
                stv(&out[(size_t)node * 128 + t * 16 + jbase], y);
            }
        }
    }
}

extern "C" void kernel_launch(void* const* d_in, const int* in_sizes, int n_in,
                              void* d_out, int out_size, void* d_ws, size_t ws_size,
                              hipStream_t stream) {
    const float* x = (const float*)d_in[0];
    const int* edge = (const int*)d_in[1];
    int E = in_sizes[1] / 2;
    const int* src = edge;
    const int* dst = edge + E;

    const float* w1l = (const float*)d_in[2];
    const float* b1  = (const float*)d_in[3];
    const float* w1r = (const float*)d_in[4];
    const float* g1  = (const float*)d_in[5];
    const float* be1 = (const float*)d_in[6];
    const float* w2l = (const float*)d_in[7];
    const float* b2  = (const float*)d_in[8];
    const float* w2r = (const float*)d_in[9];
    const float* g2  = (const float*)d_in[10];
    const float* be2 = (const float*)d_in[11];
    const float* w3l = (const float*)d_in[12];
    const float* b3  = (const float*)d_in[13];
    const float* w3r = (const float*)d_in[14];
    const float* g3  = (const float*)d_in[15];
    const float* be3 = (const float*)d_in[16];
    const float* w4l = (const float*)d_in[17];
    const float* b4  = (const float*)d_in[18];
    const float* w4r = (const float*)d_in[19];
    const float* g4  = (const float*)d_in[20];
    const float* be4 = (const float*)d_in[21];

    char* ws = (char*)d_ws;
    size_t off = 0;
    auto alloc = [&](size_t bytes) {
        void* p = ws + off;
        off = (off + bytes + 255) & ~(size_t)255;
        return p;
    };
    int* row_ptr = (int*)alloc((N_NODES + 1) * sizeof(int));
    int* blkhist = (int*)alloc((size_t)NBUCK2 * NPART * sizeof(int));
    int* blkoffs = (int*)alloc((size_t)NBUCK2 * NPART * sizeof(int));
    int* bbase2  = (int*)alloc((NBUCK2 + 1) * sizeof(int));
    unsigned int* pairs = (unsigned int*)alloc((size_t)E * sizeof(unsigned int));
    int* colx    = (int*)alloc((size_t)E * sizeof(int));
    float* wt1   = (float*)alloc(18 * 64 * sizeof(float));
    unsigned short* bp2 = (unsigned short*)alloc(128 * 128 * sizeof(short));
    unsigned short* bp3 = (unsigned short*)alloc(256 * 128 * sizeof(short));
    unsigned short* bp4 = (unsigned short*)alloc(256 * 128 * sizeof(short));
    float* m9    = (float*)alloc((size_t)N_NODES * 9 * sizeof(float));
    unsigned short* mbf = (unsigned short*)alloc((size_t)N_NODES * 128 * sizeof(short));
    unsigned short* h1  = (unsigned short*)alloc((size_t)N_NODES * 64 * sizeof(short));
    unsigned short* h2  = (unsigned short*)alloc((size_t)N_NODES * 128 * sizeof(short));
    unsigned short* h3  = (unsigned short*)alloc((size_t)N_NODES * 128 * sizeof(short));
    (void)ws_size;

    part_hist<<<NPART, 256, 0, stream>>>(dst, E, blkhist);
    part_offsets<<<1, 64, 0, stream>>>(blkhist, blkoffs, bbase2, row_ptr, E);
    part_scatter<<<NPART, 256, 0, stream>>>(src, dst, E, blkoffs, pairs);
    bucket_build2<<<NBUCK2, 1024, 0, stream>>>(pairs, bbase2, row_ptr, colx);

    wtrans_kernel<<<(18 * 64 + 255) / 256, 256, 0, stream>>>(w1l, w1r, 9, 64, wt1);
    packw_kernel<<<(128 * 128 + 255) / 256, 256, 0, stream>>>(w2l, w2r, 64, bp2);
    packw_kernel<<<(256 * 128 + 255) / 256, 256, 0, stream>>>(w3l, w3r, 128, bp3);
    packw_kernel<<<(256 * 128 + 255) / 256, 256, 0, stream>>>(w4l, w4r, 128, bp4);

    float* out = (float*)d_out;
    int AGB = (N_NODES * 64 + 255) / 256;  // one wave per node
    int LNB = (N_NODES + 63) / 64;         // 64 nodes per block

    // layer 1: 9 -> 64 (fp32 compute, bf16 out)
    agg9_kernel<<<AGB, 256, 0, stream>>>(x, row_ptr, colx, m9, N_NODES);
    linear_ln_kernel<9, 64, true, __hip_bfloat16><<<LNB, 256, 0, stream>>>(
        m9, x, wt1, b1, g1, be1, (__hip_bfloat16*)h1, N_NODES);
    // layer 2: 64 -> 128
    agg64_kernel<<<AGB, 256, 0, stream>>>(h1, row_ptr, colx, mbf, N_NODES);
    mfma_linear_ln<64, true, __hip_bfloat16><<<LNB, 256, 0, stream>>>(
        mbf, h1, bp2, b2, g2, be2, (__hip_bfloat16*)h2, N_NODES);
    // layer 3: 128 -> 128
    agg128_kernel<<<AGB, 256, 0, stream>>>(h2, row_ptr, colx, mbf, N_NODES);
    mfma_linear_ln<128, true, __hip_bfloat16><<<LNB, 256, 0, stream>>>(
        mbf, h2, bp3, b3, g3, be3, (__hip_bfloat16*)h3, N_NODES);
    // layer 4: 128 -> 128 (no ReLU, fp32 out)
    agg128_kernel<<<AGB, 256, 0, stream>>>(h3, row_ptr, colx, mbf, N_NODES);
    mfma_linear_ln<128, false, float><<<LNB, 256, 0, stream>>>(
        mbf, h3, bp4, b4, g4, be4, out, N_NODES);
}

// Round 5
// 388.409 us; speedup vs baseline: 1.6015x; 1.0772x over previous
//
#include <hip/hip_runtime.h>
#include <hip/hip_bf16.h>
#include <math.h>

#define N_NODES 100000
#define EPS 1e-5f
#define B2SH 11
#define NPB2 2048
#define NBUCK2 ((N_NODES + NPB2 - 1) / NPB2)  // 49
#define NPART 256

typedef __attribute__((ext_vector_type(8))) short bf16x8;
typedef __attribute__((ext_vector_type(4))) float f32x4;

__device__ __forceinline__ float bflo(unsigned int u) { return __uint_as_float(u << 16); }
__device__ __forceinline__ float bfhi(unsigned int u) { return __uint_as_float(u & 0xffff0000u); }
__device__ __forceinline__ unsigned short fbits(float f) {
    __hip_bfloat16 h = __float2bfloat16(f);
    return *reinterpret_cast<unsigned short*>(&h);
}
__device__ __forceinline__ void stv(float* p, float y) { *p = y; }
__device__ __forceinline__ void stv(__hip_bfloat16* p, float y) { *p = __float2bfloat16(y); }

// ---------------- atomic-free two-level CSR build ----------------
__global__ void part_hist(const int* __restrict__ dst, int E, int* __restrict__ blkhist) {
    __shared__ int h[NBUCK2];
    int b = blockIdx.x;
    int slice = (E + NPART - 1) / NPART;
    int s0 = b * slice;
    int s1 = min(E, s0 + slice);
    for (int i = threadIdx.x; i < NBUCK2; i += 256) h[i] = 0;
    __syncthreads();
    for (int e = s0 + threadIdx.x; e < s1; e += 256) atomicAdd(&h[dst[e] >> B2SH], 1);
    __syncthreads();
    for (int i = threadIdx.x; i < NBUCK2; i += 256) blkhist[i * NPART + b] = h[i];
}

__global__ void part_offsets(const int* __restrict__ blkhist, int* __restrict__ blkoffs,
                             int* __restrict__ bbase2, int* __restrict__ row_ptr, int E) {
    __shared__ int tot[NBUCK2];
    __shared__ int sbase[NBUCK2 + 1];
    int j = threadIdx.x;
    if (j < NBUCK2) {
        int run = 0;
#pragma unroll 8
        for (int b = 0; b < NPART; ++b) {
            blkoffs[j * NPART + b] = run;
            run += blkhist[j * NPART + b];
        }
        tot[j] = run;
    }
    __syncthreads();
    if (j == 0) {
        int run = 0;
        for (int i = 0; i < NBUCK2; ++i) {
            sbase[i] = run;
            run += tot[i];
        }
        sbase[NBUCK2] = run;
        row_ptr[N_NODES] = E;
    }
    __syncthreads();
    if (j <= NBUCK2) bbase2[j] = sbase[j];
    if (j < NBUCK2) {
        int base = sbase[j];
#pragma unroll 8
        for (int b = 0; b < NPART; ++b) blkoffs[j * NPART + b] += base;
    }
}

__global__ void part_scatter(const int* __restrict__ src, const int* __restrict__ dst, int E,
                             const int* __restrict__ blkoffs, unsigned int* __restrict__ pairs) {
    __shared__ int pos[NBUCK2];
    int b = blockIdx.x;
    int slice = (E + NPART - 1) / NPART;
    int s0 = b * slice;
    int s1 = min(E, s0 + slice);
    for (int i = threadIdx.x; i < NBUCK2; i += 256) pos[i] = blkoffs[i * NPART + b];
    __syncthreads();
    for (int e = s0 + threadIdx.x; e < s1; e += 256) {
        int d = dst[e];
        int jb = d >> B2SH;
        int p = atomicAdd(&pos[jb], 1);
        pairs[p] = ((unsigned int)src[e] << B2SH) | (unsigned int)(d & (NPB2 - 1));
    }
}

__global__ __launch_bounds__(1024) void bucket_build2(const unsigned int* __restrict__ pairs,
                                                      const int* __restrict__ bbase2,
                                                      int* __restrict__ row_ptr,
                                                      int* __restrict__ col) {
    __shared__ int lcnt[NPB2];
    __shared__ int lofs[NPB2];
    __shared__ int part[1024];
    int bk = blockIdx.x;
    int base = bbase2[bk];
    int cntb = bbase2[bk + 1] - base;
    int node0 = bk << B2SH;
    int t = threadIdx.x;
    lcnt[t] = 0;
    lcnt[t + 1024] = 0;
    __syncthreads();
    for (int i = t; i < cntb; i += 1024) atomicAdd(&lcnt[pairs[base + i] & (NPB2 - 1)], 1);
    __syncthreads();
    int a0 = lcnt[2 * t], a1 = lcnt[2 * t + 1];
    part[t] = a0 + a1;
    __syncthreads();
    for (int off = 1; off < 1024; off <<= 1) {
        int v = (t >= off) ? part[t - off] : 0;
        __syncthreads();
        part[t] += v;
        __syncthreads();
    }
    int excl = part[t] - (a0 + a1);
    lofs[2 * t] = excl;
    lofs[2 * t + 1] = excl + a0;
    __syncthreads();
#pragma unroll
    for (int k = 0; k < 2; ++k) {
        int ln = 2 * t + k;
        int node = node0 + ln;
        if (node < N_NODES) row_ptr[node] = base + lofs[ln];
    }
    lcnt[t] = 0;
    lcnt[t + 1024] = 0;
    __syncthreads();
    for (int i = t; i < cntb; i += 1024) {
        unsigned int v = pairs[base + i];
        int ld = v & (NPB2 - 1);
        int s = v >> B2SH;
        int p = base + lofs[ld] + atomicAdd(&lcnt[ld], 1);
        col[p] = s;
    }
}

// ---------------- aggregation (predicated, no serial tails) ----------------
// layer1: x fp32, d=9; 7 lane-groups of 9; 4-deep predicated unroll of stride-7 walk
__global__ void agg9_kernel(const float* __restrict__ x, const int* __restrict__ row_ptr,
                            const int* __restrict__ col, float* __restrict__ mean, int n) {
    int node = (blockIdx.x * blockDim.x + threadIdx.x) >> 6;
    int lane = threadIdx.x & 63;
    int wv = threadIdx.x >> 6;
    __shared__ float red[4][64];
    float acc = 0.f;
    int start = 0, end = 0;
    if (node < n) {
        start = row_ptr[node];
        end = row_ptr[node + 1];
        int g = lane / 9;
        int f = lane - g * 9;
        if (g < 7 && end > start) {
            for (int p = start + g; p < end; p += 28) {
#pragma unroll
                for (int i = 0; i < 4; ++i) {
                    int q = p + i * 7;
                    int idx = (q < end) ? q : end - 1;
                    float v = x[(size_t)col[idx] * 9 + f];
                    if (q >= end) v = 0.f;
                    acc += v;
                }
            }
        }
    }
    red[wv][lane] = acc;
    __syncthreads();
    if (node < n && lane < 9) {
        float s = red[wv][lane];
#pragma unroll
        for (int k = 1; k < 7; ++k) s += red[wv][lane + 9 * k];
        float inv = 1.f / fmaxf((float)(end - start), 1.f);
        mean[(size_t)node * 9 + lane] = s * inv;
    }
}

// bf16 d=64: one wave per node, lane = column; 16-wide predicated batches
__global__ void agg64_kernel(const unsigned short* __restrict__ h, const int* __restrict__ row_ptr,
                             const int* __restrict__ col, unsigned short* __restrict__ mean, int n) {
    int node = (blockIdx.x * blockDim.x + threadIdx.x) >> 6;
    int lane = threadIdx.x & 63;
    if (node >= n) return;
    int start = row_ptr[node], end = row_ptr[node + 1];
    int deg = end - start;
    if (deg <= 0) {
        mean[(size_t)node * 64 + lane] = 0;
        return;
    }
    float inv = 1.f / (float)deg;
    float acc = 0.f;
    for (int p = start; p < end; p += 16) {
#pragma unroll
        for (int i = 0; i < 16; ++i) {
            int q = p + i;
            int idx = (q < end) ? q : end - 1;
            unsigned int u = (unsigned int)h[(size_t)col[idx] * 64 + lane];
            if (q >= end) u = 0u;
            acc += bflo(u);
        }
    }
    mean[(size_t)node * 64 + lane] = fbits(acc * inv);
}

// bf16 d=128: one wave per node, lane covers 2 columns; 16-wide predicated batches
__global__ void agg128_kernel(const unsigned short* __restrict__ h, const int* __restrict__ row_ptr,
                              const int* __restrict__ col, unsigned short* __restrict__ mean, int n) {
    int node = (blockIdx.x * blockDim.x + threadIdx.x) >> 6;
    int lane = threadIdx.x & 63;
    if (node >= n) return;
    int start = row_ptr[node], end = row_ptr[node + 1];
    int deg = end - start;
    if (deg <= 0) {
        *(unsigned int*)&mean[(size_t)node * 128 + lane * 2] = 0u;
        return;
    }
    float inv = 1.f / (float)deg;
    float ax = 0.f, ay = 0.f;
    for (int p = start; p < end; p += 16) {
#pragma unroll
        for (int i = 0; i < 16; ++i) {
            int q = p + i;
            int idx = (q < end) ? q : end - 1;
            unsigned int u = *(const unsigned int*)&h[(size_t)col[idx] * 128 + lane * 2];
            if (q >= end) u = 0u;
            ax += bflo(u);
            ay += bfhi(u);
        }
    }
    unsigned int lo = fbits(ax * inv);
    unsigned int hi = fbits(ay * inv);
    *(unsigned int*)&mean[(size_t)node * 128 + lane * 2] = lo | (hi << 16);
}

// ---------------- weight prep ----------------
__global__ void wtrans_kernel(const float* __restrict__ wl, const float* __restrict__ wr,
                              int din, int dout, float* __restrict__ wt) {
    int i = blockIdx.x * blockDim.x + threadIdx.x;
    int K2 = 2 * din;
    if (i >= K2 * dout) return;
    int k = i / dout, j = i % dout;
    wt[k * dout + j] = (k < din) ? wl[j * din + k] : wr[j * din + (k - din)];
}

__global__ void packw_kernel(const float* __restrict__ wl, const float* __restrict__ wr,
                             int din, unsigned short* __restrict__ bpack) {
    int K2 = 2 * din;
    int total = K2 * 128;
    int i = blockIdx.x * 256 + threadIdx.x;
    if (i >= total) return;
    int e = i & 7;
    int lane = (i >> 3) & 63;
    int rest = i >> 9;
    int KSTEPS = din / 16;
    int t = rest / KSTEPS, ks = rest % KSTEPS;
    int j = t * 16 + (lane & 15);
    int k = ks * 32 + (lane >> 4) * 8 + e;
    float w = (k < din) ? wl[j * din + k] : wr[j * din + (k - din)];
    bpack[i] = fbits(w);
}

// ---------------- layer1 fp32 linear + LN + ReLU ----------------
template <int DIN, int DOUT, bool RELU, typename OT>
__global__ __launch_bounds__(256) void linear_ln_kernel(
    const float* __restrict__ meanp, const float* __restrict__ hp,
    const float* __restrict__ wt, const float* __restrict__ bias,
    const float* __restrict__ g, const float* __restrict__ be,
    OT* __restrict__ out, int n) {
    constexpr int K2 = 2 * DIN;
    constexpr int NCOL = DOUT / 4;
    constexpr int NROW = 256 / NCOL;
    constexpr int TN = 4 * NROW;
    constexpr int ASTR = TN + 4;
    constexpr int OSTR = DOUT + 4;
    constexpr int SMEMF = (K2 * ASTR > TN * OSTR) ? K2 * ASTR : TN * OSTR;
    __shared__ float smem[SMEMF];

    int tid = threadIdx.x;
    int n0base = blockIdx.x * TN;

    for (int idx = tid; idx < TN * K2; idx += 256) {
        int nn = idx / K2;
        int k = idx % K2;
        int node = n0base + nn;
        float v = 0.f;
        if (node < n)
            v = (k < DIN) ? meanp[(size_t)node * DIN + k] : hp[(size_t)node * DIN + (k - DIN)];
        smem[k * ASTR + nn] = v;
    }
    __syncthreads();

    int colt = tid % NCOL;
    int rowt = tid / NCOL;
    int j0 = colt * 4;
    int nn0 = rowt * 4;

    float acc[4][4];
#pragma unroll
    for (int i = 0; i < 4; ++i)
#pragma unroll
        for (int j = 0; j < 4; ++j) acc[i][j] = 0.f;

#pragma unroll 2
    for (int k = 0; k < K2; ++k) {
        float4 a = *(const float4*)&smem[k * ASTR + nn0];
        float4 w = *(const float4*)&wt[k * DOUT + j0];
        acc[0][0] = fmaf(a.x, w.x, acc[0][0]);
        acc[0][1] = fmaf(a.x, w.y, acc[0][1]);
        acc[0][2] = fmaf(a.x, w.z, acc[0][2]);
        acc[0][3] = fmaf(a.x, w.w, acc[0][3]);
        acc[1][0] = fmaf(a.y, w.x, acc[1][0]);
        acc[1][1] = fmaf(a.y, w.y, acc[1][1]);
        acc[1][2] = fmaf(a.y, w.z, acc[1][2]);
        acc[1][3] = fmaf(a.y, w.w, acc[1][3]);
        acc[2][0] = fmaf(a.z, w.x, acc[2][0]);
        acc[2][1] = fmaf(a.z, w.y, acc[2][1]);
        acc[2][2] = fmaf(a.z, w.z, acc[2][2]);
        acc[2][3] = fmaf(a.z, w.w, acc[2][3]);
        acc[3][0] = fmaf(a.w, w.x, acc[3][0]);
        acc[3][1] = fmaf(a.w, w.y, acc[3][1]);
        acc[3][2] = fmaf(a.w, w.z, acc[3][2]);
        acc[3][3] = fmaf(a.w, w.w, acc[3][3]);
    }
    __syncthreads();

    float4 bj = *(const float4*)&bias[j0];
#pragma unroll
    for (int i = 0; i < 4; ++i) {
        float4 o;
        o.x = acc[i][0] + bj.x;
        o.y = acc[i][1] + bj.y;
        o.z = acc[i][2] + bj.z;
        o.w = acc[i][3] + bj.w;
        *(float4*)&smem[(nn0 + i) * OSTR + j0] = o;
    }
    __syncthreads();

    int wid = tid >> 6, lane = tid & 63;
    for (int nn = wid; nn < TN; nn += 4) {
        int node = n0base + nn;
        if (node >= n) continue;
        float v0 = smem[nn * OSTR + lane];
        float v1 = (DOUT == 128) ? smem[nn * OSTR + 64 + lane] : 0.f;
        float s = v0 + v1;
        float ss = v0 * v0 + v1 * v1;
#pragma unroll
        for (int off = 32; off > 0; off >>= 1) {
            s += __shfl_xor(s, off);
            ss += __shfl_xor(ss, off);
        }
        float mu = s / DOUT;
        float var = ss / DOUT - mu * mu;
        float inv = rsqrtf(var + EPS);
        float y0 = (v0 - mu) * inv * g[lane] + be[lane];
        if (RELU) y0 = fmaxf(y0, 0.f);
        stv(&out[(size_t)node * DOUT + lane], y0);
        if (DOUT == 128) {
            float y1 = (v1 - mu) * inv * g[64 + lane] + be[64 + lane];
            if (RELU) y1 = fmaxf(y1, 0.f);
            stv(&out[(size_t)node * DOUT + 64 + lane], y1);
        }
    }
}

// ---------------- bf16 MFMA linear (concat-K) + LN + optional ReLU ----------
template <int DIN, bool RELU, typename OT>
__global__ __launch_bounds__(256) void mfma_linear_ln(
    const unsigned short* __restrict__ meanb, const unsigned short* __restrict__ hb,
    const unsigned short* __restrict__ bpack, const float* __restrict__ bias,
    const float* __restrict__ g, const float* __restrict__ be, OT* __restrict__ out, int n) {
    constexpr int KSTEPS = DIN / 16;
    int tid = threadIdx.x;
    int w = tid >> 6, l = tid & 63;
    int n0 = blockIdx.x * 64 + w * 16;
    int arow = l & 15;
    int koff = (l >> 4) * 8;
    int anode = n0 + arow;
    if (anode >= n) anode = n - 1;
    const unsigned short* mrow = meanb + (size_t)anode * DIN;
    const unsigned short* hrow = hb + (size_t)anode * DIN;

    f32x4 acc[8];
#pragma unroll
    for (int t = 0; t < 8; ++t) acc[t] = (f32x4){0.f, 0.f, 0.f, 0.f};

#pragma unroll
    for (int ks = 0; ks < KSTEPS; ++ks) {
        int k = ks * 32 + koff;
        const unsigned short* ap = (k < DIN) ? (mrow + k) : (hrow + (k - DIN));
        bf16x8 a = *(const bf16x8*)ap;
#pragma unroll
        for (int t = 0; t < 8; ++t) {
            bf16x8 b = *(const bf16x8*)(bpack + (((size_t)t * KSTEPS + ks) * 64 + l) * 8);
            acc[t] = __builtin_amdgcn_mfma_f32_16x16x32_bf16(a, b, acc[t], 0, 0, 0);
        }
    }

    int jbase = l & 15;
    float bj[8], gj[8], bej[8];
#pragma unroll
    for (int t = 0; t < 8; ++t) {
        bj[t] = bias[t * 16 + jbase];
        gj[t] = g[t * 16 + jbase];
        bej[t] = be[t * 16 + jbase];
    }
#pragma unroll
    for (int r = 0; r < 4; ++r) {
        float v[8];
        float s = 0.f, ss = 0.f;
#pragma unroll
        for (int t = 0; t < 8; ++t) {
            v[t] = acc[t][r] + bj[t];
            s += v[t];
            ss += v[t] * v[t];
        }
#pragma unroll
        for (int off = 1; off < 16; off <<= 1) {
            s += __shfl_xor(s, off);
            ss += __shfl_xor(ss, off);
        }
        float mu = s * (1.f / 128.f);
        float var = ss * (1.f / 128.f) - mu * mu;
        float inv = rsqrtf(var + EPS);
        int node = n0 + (l >> 4) * 4 + r;
        if (node < n) {
#pragma unroll
            for (int t = 0; t < 8; ++t) {
                float y = (v[t] - mu) * inv * gj[t] + bej[t];
                if (RELU) y = fmaxf(y, 0.f);
                stv(&out[(size_t)node * 128 + t * 16 + jbase], y);
            }
        }
    }
}

extern "C" void kernel_launch(void* const* d_in, const int* in_sizes, int n_in,
                              void* d_out, int out_size, void* d_ws, size_t ws_size,
                              hipStream_t stream) {
    const float* x = (const float*)d_in[0];
    const int* edge = (const int*)d_in[1];
    int E = in_sizes[1] / 2;
    const int* src = edge;
    const int* dst = edge + E;

    const float* w1l = (const float*)d_in[2];
    const float* b1  = (const float*)d_in[3];
    const float* w1r = (const float*)d_in[4];
    const float* g1  = (const float*)d_in[5];
    const float* be1 = (const float*)d_in[6];
    const float* w2l = (const float*)d_in[7];
    const float* b2  = (const float*)d_in[8];
    const float* w2r = (const float*)d_in[9];
    const float* g2  = (const float*)d_in[10];
    const float* be2 = (const float*)d_in[11];
    const float* w3l = (const float*)d_in[12];
    const float* b3  = (const float*)d_in[13];
    const float* w3r = (const float*)d_in[14];
    const float* g3  = (const float*)d_in[15];
    const float* be3 = (const float*)d_in[16];
    const float* w4l = (const float*)d_in[17];
    const float* b4  = (const float*)d_in[18];
    const float* w4r = (const float*)d_in[19];
    const float* g4  = (const float*)d_in[20];
    const float* be4 = (const float*)d_in[21];

    char* ws = (char*)d_ws;
    size_t off = 0;
    auto alloc = [&](size_t bytes) {
        void* p = ws + off;
        off = (off + bytes + 255) & ~(size_t)255;
        return p;
    };
    int* row_ptr = (int*)alloc((N_NODES + 1) * sizeof(int));
    int* blkhist = (int*)alloc((size_t)NBUCK2 * NPART * sizeof(int));
    int* blkoffs = (int*)alloc((size_t)NBUCK2 * NPART * sizeof(int));
    int* bbase2  = (int*)alloc((NBUCK2 + 1) * sizeof(int));
    unsigned int* pairs = (unsigned int*)alloc((size_t)E * sizeof(unsigned int));
    int* colx    = (int*)alloc((size_t)E * sizeof(int));
    float* wt1   = (float*)alloc(18 * 64 * sizeof(float));
    unsigned short* bp2 = (unsigned short*)alloc(128 * 128 * sizeof(short));
    unsigned short* bp3 = (unsigned short*)alloc(256 * 128 * sizeof(short));
    unsigned short* bp4 = (unsigned short*)alloc(256 * 128 * sizeof(short));
    float* m9    = (float*)alloc((size_t)N_NODES * 9 * sizeof(float));
    unsigned short* mbf = (unsigned short*)alloc((size_t)N_NODES * 128 * sizeof(short));
    unsigned short* h1  = (unsigned short*)alloc((size_t)N_NODES * 64 * sizeof(short));
    unsigned short* h2  = (unsigned short*)alloc((size_t)N_NODES * 128 * sizeof(short));
    unsigned short* h3  = (unsigned short*)alloc((size_t)N_NODES * 128 * sizeof(short));
    (void)ws_size;

    part_hist<<<NPART, 256, 0, stream>>>(dst, E, blkhist);
    part_offsets<<<1, 64, 0, stream>>>(blkhist, blkoffs, bbase2, row_ptr, E);
    part_scatter<<<NPART, 256, 0, stream>>>(src, dst, E, blkoffs, pairs);
    bucket_build2<<<NBUCK2, 1024, 0, stream>>>(pairs, bbase2, row_ptr, colx);

    wtrans_kernel<<<(18 * 64 + 255) / 256, 256, 0, stream>>>(w1l, w1r, 9, 64, wt1);
    packw_kernel<<<(128 * 128 + 255) / 256, 256, 0, stream>>>(w2l, w2r, 64, bp2);
    packw_kernel<<<(256 * 128 + 255) / 256, 256, 0, stream>>>(w3l, w3r, 128, bp3);
    packw_kernel<<<(256 * 128 + 255) / 256, 256, 0, stream>>>(w4l, w4r, 128, bp4);

    float* out = (float*)d_out;
    int AGB = (N_NODES * 64 + 255) / 256;  // one wave per node
    int LNB = (N_NODES + 63) / 64;         // 64 nodes per block

    // layer 1: 9 -> 64 (fp32 compute, bf16 out)
    agg9_kernel<<<AGB, 256, 0, stream>>>(x, row_ptr, colx, m9, N_NODES);
    linear_ln_kernel<9, 64, true, __hip_bfloat16><<<LNB, 256, 0, stream>>>(
        m9, x, wt1, b1, g1, be1, (__hip_bfloat16*)h1, N_NODES);
    // layer 2: 64 -> 128
    agg64_kernel<<<AGB, 256, 0, stream>>>(h1, row_ptr, colx, mbf, N_NODES);
    mfma_linear_ln<64, true, __hip_bfloat16><<<LNB, 256, 0, stream>>>(
        mbf, h1, bp2, b2, g2, be2, (__hip_bfloat16*)h2, N_NODES);
    // layer 3: 128 -> 128
    agg128_kernel<<<AGB, 256, 0, stream>>>(h2, row_ptr, colx, mbf, N_NODES);
    mfma_linear_ln<128, true, __hip_bfloat16><<<LNB, 256, 0, stream>>>(
        mbf, h2, bp3, b3, g3, be3, (__hip_bfloat16*)h3, N_NODES);
    // layer 4: 128 -> 128 (no ReLU, fp32 out)
    agg128_kernel<<<AGB, 256, 0, stream>>>(h3, row_ptr, colx, mbf, N_NODES);
    mfma_linear_ln<128, false, float><<<LNB, 256, 0, stream>>>(
        mbf, h3, bp4, b4, g4, be4, out, N_NODES);
}